// Round 8
// baseline (280.750 us; speedup 1.0000x reference)
//
#include <hip/hip_runtime.h>
#include <math.h>

// Shapes: B=32, S=512, I=64, H=512, E=8, P=96, O=64, EM=512; D = S*I = 32768.
#define DIMK 32768

__device__ __forceinline__ void fma4(float4& a, float s, const float4 w) {
  a.x += s * w.x; a.y += s * w.y; a.z += s * w.z; a.w += s * w.w;
}

__device__ __forceinline__ float fsel(const float4& v, int kk) {
  return kk == 0 ? v.x : kk == 1 ? v.y : kk == 2 ? v.z : v.w;
}

__device__ __forceinline__ float wave_sum(float v) {
  v += __shfl_xor(v, 1); v += __shfl_xor(v, 2); v += __shfl_xor(v, 4);
  v += __shfl_xor(v, 8); v += __shfl_xor(v, 16); v += __shfl_xor(v, 32);
  return v;
}

// sum across a 16-lane group (for 64-value rows held 4-per-thread by 16 lanes)
__device__ __forceinline__ float group16_sum(float v) {
  v += __shfl_xor(v, 1); v += __shfl_xor(v, 2);
  v += __shfl_xor(v, 4); v += __shfl_xor(v, 8);
  return v;
}

// Direct global->LDS DMA, 16 B per lane (dest = wave-uniform base + lane*16).
__device__ __forceinline__ void gld_lds16(const float* g, float* l) {
  __builtin_amdgcn_global_load_lds(
      (const __attribute__((address_space(1))) void*)g,
      (__attribute__((address_space(3))) void*)l, 16, 0, 0);
}

__device__ __forceinline__ float block_sum(float v, float* red, int n) {
  int t = threadIdx.x;
  red[t] = v;
  __syncthreads();
  for (int s = n >> 1; s > 0; s >>= 1) {
    if (t < s) red[t] += red[t + s];
    __syncthreads();
  }
  float r = red[0];
  __syncthreads();
  return r;
}

// ---------------------------------------------------------------------------
// gemm1: part[ks][b][m] = x(32 x 32768)[,k-slice ks] @ gW1[k-slice][m-tile].
// grid (4 mt, 128 ks) = 512 blocks (2/CU), block 256. A staged once (32 KB);
// W double-buffered 32k x 128m (16 KB) sub-stages, both via global_load_lds
// width=16. LDS 64 KB. [round-2 proven form, unchanged]
__global__ __launch_bounds__(256) void gemm1(const float* __restrict__ x,
                                             const float* __restrict__ gW1,
                                             float* __restrict__ part) {
  const int mt = blockIdx.x, ks = blockIdx.y;
  const int m0 = mt * 128, k0 = ks * 256;
  const int t = threadIdx.x;
  __shared__ float As[32 * 256];     // [b][k], 32 KB
  __shared__ float Ws[2][32 * 128];  // [k][m] sub-stage, 16 KB each

  const float* Wp = gW1 + (size_t)k0 * 512 + m0;

#pragma unroll
  for (int j = 0; j < 8; ++j) {
    int i = t + j * 256;
    gld_lds16(x + (size_t)(i >> 6) * DIMK + k0 + (i & 63) * 4, &As[i * 4]);
  }
#pragma unroll
  for (int j = 0; j < 4; ++j) {
    int i = t + j * 256;
    gld_lds16(Wp + (size_t)(i >> 5) * 512 + (i & 31) * 4, &Ws[0][i * 4]);
  }

  const int mf4 = (t & 31) * 4;
  const int bg = t >> 5;
  float4 acc[4];
#pragma unroll
  for (int j = 0; j < 4; ++j) acc[j] = make_float4(0.f, 0.f, 0.f, 0.f);
  const float* a0 = &As[bg * 4 * 256];

  for (int s = 0; s < 8; ++s) {
    __syncthreads();
    if (s < 7) {
      const float* Wn = Wp + (size_t)(s + 1) * 32 * 512;
#pragma unroll
      for (int j = 0; j < 4; ++j) {
        int i = t + j * 256;
        gld_lds16(Wn + (size_t)(i >> 5) * 512 + (i & 31) * 4, &Ws[(s + 1) & 1][i * 4]);
      }
    }
    const float* Wc = Ws[s & 1];
    const int sc = s * 32;
#pragma unroll
    for (int kq = 0; kq < 8; ++kq) {
      float4 av0 = *(const float4*)(a0 + sc + kq * 4);
      float4 av1 = *(const float4*)(a0 + 256 + sc + kq * 4);
      float4 av2 = *(const float4*)(a0 + 512 + sc + kq * 4);
      float4 av3 = *(const float4*)(a0 + 768 + sc + kq * 4);
#pragma unroll
      for (int kk = 0; kk < 4; ++kk) {
        float4 wv = *(const float4*)&Wc[(kq * 4 + kk) * 128 + mf4];
        fma4(acc[0], fsel(av0, kk), wv);
        fma4(acc[1], fsel(av1, kk), wv);
        fma4(acc[2], fsel(av2, kk), wv);
        fma4(acc[3], fsel(av3, kk), wv);
      }
    }
  }

  float* op = part + ((size_t)ks * 32 + bg * 4) * 512 + m0 + mf4;
#pragma unroll
  for (int j = 0; j < 4; ++j) *(float4*)(op + (size_t)j * 512) = acc[j];
}

// ---------------------------------------------------------------------------
// pr_he: grid 272, block 256. Independent work fused by grid partition:
// bid<256 -> part_red (pre[c][b][m] = sum 16 ks-slices); bid>=256 -> he_k.
__global__ __launch_bounds__(256) void pr_he(const float* __restrict__ part,
                                             float* __restrict__ pre,
                                             const float* __restrict__ x,
                                             const float* __restrict__ eW1,
                                             const float* __restrict__ eb1,
                                             float* __restrict__ he_all) {
  __shared__ float sm[18432];  // he_k: xs 2048 + Ws 16384 (72 KB)
  const int bid = blockIdx.x, t = threadIdx.x;
  if (bid < 256) {
    const int b = bid & 31, c = bid >> 5;
#pragma unroll
    for (int h = 0; h < 2; ++h) {
      int m = t + h * 256;
      float a = 0.f;
      const float* p = part + ((size_t)c * 16 * 32 + b) * 512 + m;
#pragma unroll
      for (int i = 0; i < 16; ++i) a += p[(size_t)i * 16384];
      pre[((size_t)c * 32 + b) * 512 + m] = a;
    }
  } else {
    const int idx = bid - 256;
    const int e = idx >> 1, hs = idx & 1;
    float* xs = sm;          // 32 x 64
    float* Ws = sm + 2048;   // 64 x 256
    for (int i = t; i < 512; i += 256) {
      int b = i >> 4, q = i & 15;
      *(float4*)&xs[b * 64 + q * 4] = *(const float4*)(x + (size_t)b * DIMK + 32704 + q * 4);
    }
    const float* w1 = eW1 + (size_t)e * 64 * 512 + hs * 256;
    for (int i = t; i < 64 * 64; i += 256) {
      int k = i >> 6, q = i & 63;
      *(float4*)&Ws[k * 256 + q * 4] = *(const float4*)(w1 + (size_t)k * 512 + q * 4);
    }
    __syncthreads();
    float acc[32];
#pragma unroll
    for (int b = 0; b < 32; ++b) acc[b] = 0.f;
#pragma unroll 4
    for (int k = 0; k < 64; ++k) {
      float wk = Ws[k * 256 + t];
#pragma unroll
      for (int b = 0; b < 32; ++b) acc[b] += xs[b * 64 + k] * wk;
    }
    float bb = eb1[e * 512 + hs * 256 + t];
    for (int b = 0; b < 32; ++b)
      he_all[((size_t)e * 32 + b) * 512 + hs * 256 + t] = fmaxf(acc[b] + bb, 0.f);
  }
}

// ---------------------------------------------------------------------------
// ln_eg: grid 544, block 256. bid<32 -> LN1; bid>=32 -> expert gemm KC=64
// (512 blocks: 8 mt x 8 kq x 8 e). [round-7 proven form]
__global__ __launch_bounds__(256) void ln_eg(const float* __restrict__ pre,
                                             const float* __restrict__ gb1,
                                             const float* __restrict__ g,
                                             const float* __restrict__ bt,
                                             float* __restrict__ h1,
                                             const float* __restrict__ he_all,
                                             const float* __restrict__ eW2,
                                             float* __restrict__ epart) {
  __shared__ float sm[6272];  // gemm: Ws 64*64 + As 32*68; LN: sm[0..4) = red4
  const int bid = blockIdx.x, t = threadIdx.x;
  if (bid < 32) {
    const int b = bid;
    float a0 = gb1[t], a1 = gb1[t + 256];
    for (int kq = 0; kq < 8; ++kq) {
      const float* p = pre + ((size_t)kq * 32 + b) * 512;
      a0 += p[t]; a1 += p[t + 256];
    }
    const int lane = t & 63, wid = t >> 6;
    float s = wave_sum(a0 + a1);
    if (lane == 0) sm[wid] = s;
    __syncthreads();
    float mean = (sm[0] + sm[1] + sm[2] + sm[3]) * (1.f / 512.f);
    float d0 = a0 - mean, d1 = a1 - mean;
    __syncthreads();
    float q = wave_sum(d0 * d0 + d1 * d1);
    if (lane == 0) sm[wid] = q;
    __syncthreads();
    float var = (sm[0] + sm[1] + sm[2] + sm[3]) * (1.f / 512.f);
    float rr = rsqrtf(var + 1e-5f);
    h1[b * 512 + t] = fmaxf(d0 * rr * g[t] + bt[t], 0.f);
    h1[b * 512 + t + 256] = fmaxf(d1 * rr * g[t + 256] + bt[t + 256], 0.f);
  } else {
    const int idx = bid - 32;
    const int mt = idx & 7, kq = (idx >> 3) & 7, e = idx >> 6;
    constexpr int KC = 64;
    float* Ws = sm;               // 64*64
    float* As = sm + KC * 64;     // 32*68
    const int m0 = mt * 64, k0 = kq * KC;
    const float* Wp = eW2 + (size_t)e * 512 * 512 + (size_t)k0 * 512 + m0;
    for (int i = t; i < KC * 16; i += 256) {
      int r = i >> 4, q = i & 15;
      *(float4*)&Ws[r * 64 + q * 4] = *(const float4*)(Wp + (size_t)r * 512 + q * 4);
    }
    const float* Ap = he_all + (size_t)e * 32 * 512 + k0;
    for (int i = t; i < 32 * (KC / 4); i += 256) {
      int b = i / (KC / 4), q = i % (KC / 4);
      *(float4*)&As[b * (KC + 4) + q * 4] = *(const float4*)(Ap + (size_t)b * 512 + q * 4);
    }
    __syncthreads();
    const int mf = t & 15, bg = t >> 4;
    const int b0 = bg * 2;
    float4 acc0 = make_float4(0.f, 0.f, 0.f, 0.f), acc1 = acc0;
    const float* a0 = &As[b0 * (KC + 4)];
    const float* a1 = &As[(b0 + 1) * (KC + 4)];
#pragma unroll 8
    for (int k = 0; k < KC; ++k) {
      float4 wv = *(const float4*)&Ws[k * 64 + mf * 4];
      fma4(acc0, a0[k], wv);
      fma4(acc1, a1[k], wv);
    }
    float* op = epart + ((size_t)(kq * 8 + e) * 32 + b0) * 512 + m0 + mf * 4;
    *(float4*)op = acc0;
    *(float4*)(op + 512) = acc1;
  }
}

// ---------------------------------------------------------------------------
// gemm_tile<KC>: C_part = A(32 x K) @ W(K x M), one (64 m x KC k) tile/block.
// grid (M/64, K/KC), block 256. [round-2 proven form]
template <int KC>
__global__ __launch_bounds__(256) void gemm_tile(const float* __restrict__ A,
                                                 const float* __restrict__ W,
                                                 float* __restrict__ outp,
                                                 int M, int aRow) {
  const int mt = blockIdx.x, kq = blockIdx.y;
  const int m0 = mt * 64, k0 = kq * KC;
  const int t = threadIdx.x;
  __shared__ float Ws[KC * 64];
  __shared__ float As[32 * (KC + 4)];
  const float* Wp = W + (size_t)k0 * M + m0;
  for (int i = t; i < KC * 16; i += 256) {
    int r = i >> 4, q = i & 15;
    *(float4*)&Ws[r * 64 + q * 4] = *(const float4*)(Wp + (size_t)r * M + q * 4);
  }
  const float* Ap = A + k0;
  for (int i = t; i < 32 * (KC / 4); i += 256) {
    int b = i / (KC / 4), q = i % (KC / 4);
    *(float4*)&As[b * (KC + 4) + q * 4] = *(const float4*)(Ap + (size_t)b * aRow + q * 4);
  }
  __syncthreads();
  const int mf = t & 15, bg = t >> 4;
  const int b0 = bg * 2;
  float4 acc0 = make_float4(0.f, 0.f, 0.f, 0.f), acc1 = acc0;
  const float* a0 = &As[b0 * (KC + 4)];
  const float* a1 = &As[(b0 + 1) * (KC + 4)];
#pragma unroll 8
  for (int k = 0; k < KC; ++k) {
    float4 wv = *(const float4*)&Ws[k * 64 + mf * 4];
    fma4(acc0, a0[k], wv);
    fma4(acc1, a1[k], wv);
  }
  float* op = outp + ((size_t)kq * 32 + b0) * M + m0 + mf * 4;
  *(float4*)op = acc0;
  *(float4*)(op + M) = acc1;
}

// ---------------------------------------------------------------------------
// red_ln: out = [relu](LN(sum_kq zp + bias)). grid 32, block M. [round-2]
__global__ void red_ln(const float* __restrict__ zp, const float* __restrict__ bias,
                       const float* __restrict__ g, const float* __restrict__ bt,
                       float* __restrict__ outp, int M, int nq, int relu) {
  const int b = blockIdx.x, t = threadIdx.x;
  __shared__ float red[512];
  float a = bias[t];
#pragma unroll 4
  for (int kq = 0; kq < nq; ++kq) a += zp[((size_t)kq * 32 + b) * M + t];
  float fM = 1.f / (float)M;
  float mean = block_sum(a, red, M) * fM;
  float d = a - mean;
  float var = block_sum(d * d, red, M) * fM;
  float v = d * rsqrtf(var + 1e-5f) * g[t] + bt[t];
  outp[b * M + t] = relu ? fmaxf(v, 0.f) : v;
}

// ---------------------------------------------------------------------------
// gate_mix: per-b mega-stage (grid 32, block 512). Fuses:
//   LN2 (h2 row -> shared only, no HBM round-trip)
//   gate gemm (emb = h2row @ gW3 + gb3; gW3 re-read 256KB x 32 = 8 MB, cheap)
//   proto distances + softmax (weights -> shared wl, no HBM)
//   ffuse (fused[b][m] = sum_e wl[e]*(sum_kq epart + eb2[e]))
__global__ __launch_bounds__(512) void gate_mix(const float* __restrict__ zp,
                                                const float* __restrict__ gb2,
                                                const float* __restrict__ g2,
                                                const float* __restrict__ bt2,
                                                const float* __restrict__ gW3,
                                                const float* __restrict__ gb3,
                                                const float* __restrict__ protos,
                                                const float* __restrict__ temp,
                                                const float* __restrict__ epart,
                                                const float* __restrict__ eb2,
                                                float* __restrict__ fused) {
  const int b = blockIdx.x, t = threadIdx.x;
  __shared__ float red[512];
  __shared__ float Arow[512];
  __shared__ float pacc[16 * 128];
  __shared__ float emb[128];
  __shared__ float d2s[8];
  __shared__ float wl[8];

  // --- LN2 ---
  float a = gb2[t];
#pragma unroll
  for (int kq = 0; kq < 8; ++kq) a += zp[((size_t)kq * 32 + b) * 512 + t];
  float mean = block_sum(a, red, 512) * (1.f / 512.f);
  float d = a - mean;
  float var = block_sum(d * d, red, 512) * (1.f / 512.f);
  Arow[t] = fmaxf(d * rsqrtf(var + 1e-5f) * g2[t] + bt2[t], 0.f);
  __syncthreads();

  // --- gate gemm: 16 kg x 32 k ---
  const int m4 = (t & 31) * 4, kg = t >> 5;
  const float* Wp = gW3 + (size_t)kg * 32 * 128 + m4;
  float4 acc = make_float4(0.f, 0.f, 0.f, 0.f);
  const float* ar = &Arow[kg * 32];
#pragma unroll 8
  for (int k = 0; k < 32; ++k) {
    float4 wv = *(const float4*)(Wp + (size_t)k * 128);
    fma4(acc, ar[k], wv);
  }
  *(float4*)&pacc[kg * 128 + m4] = acc;
  __syncthreads();
  if (t < 128) {
    float e = gb3[t];
#pragma unroll
    for (int k2 = 0; k2 < 16; ++k2) e += pacc[k2 * 128 + t];
    emb[t] = e;
  }
  __syncthreads();

  // --- distances (8 waves, one expert each) + softmax ---
  const int lane = t & 63, wid = t >> 6;
  float dd0 = emb[lane] - protos[wid * 128 + lane];
  float dd1 = emb[lane + 64] - protos[wid * 128 + 64 + lane];
  float q = wave_sum(dd0 * dd0 + dd1 * dd1);
  if (lane == 0) d2s[wid] = q;
  __syncthreads();
  if (t == 0) {
    float tt = fminf(fmaxf(temp[0], 0.1f), 5.0f);
    float lg[8], mx = -1e30f;
#pragma unroll
    for (int e = 0; e < 8; ++e) {
      float dist = sqrtf(fmaxf(d2s[e], 1e-12f));
      lg[e] = -dist / tt;
      mx = fmaxf(mx, lg[e]);
    }
    float se = 0.f;
#pragma unroll
    for (int e = 0; e < 8; ++e) { lg[e] = expf(lg[e] - mx); se += lg[e]; }
#pragma unroll
    for (int e = 0; e < 8; ++e) wl[e] = lg[e] / se;
  }
  __syncthreads();

  // --- ffuse (1 m per thread) ---
  float fa = 0.f;
#pragma unroll
  for (int e = 0; e < 8; ++e) {
    float s = eb2[e * 512 + t];
#pragma unroll
    for (int kq = 0; kq < 8; ++kq)
      s += epart[(((size_t)kq * 8 + e) * 32 + b) * 512 + t];
    fa += wl[e] * s;
  }
  fused[b * 512 + t] = fa;
}

// ---------------------------------------------------------------------------
// pgemm_ln: out[b][pi][o] = LN_o(pp[b] @ pW2[:, pi*64+o] + pb2). grid 96
// (one pi per block), block 256, KC=256 (full K -> no split-k partials).
// The 64-o row for each b lives in one 16-lane group (4 o per thread) ->
// LN via group16 shfl reduction, written directly to the final output.
// Replaces gemm_tile(pW2) + fin_red and the 3 MB fpart round-trip.
// LDS 98.8 KB (gfx950 allows up to 160 KB/block; 96 blocks, 1/CU).
__global__ __launch_bounds__(256) void pgemm_ln(const float* __restrict__ pp,
                                                const float* __restrict__ pW2,
                                                const float* __restrict__ pb2,
                                                const float* __restrict__ ong,
                                                const float* __restrict__ onb,
                                                float* __restrict__ outp) {
  const int pi = blockIdx.x;
  const int m0 = pi * 64;
  const int t = threadIdx.x;
  __shared__ float Ws[256 * 64];   // 64 KB: pW2 column tile
  __shared__ float As[32 * 260];   // 33.3 KB: full pp
  const float* Wp = pW2 + m0;
  for (int i = t; i < 4096; i += 256) {
    int r = i >> 4, q = i & 15;
    *(float4*)&Ws[r * 64 + q * 4] = *(const float4*)(Wp + (size_t)r * 6144 + q * 4);
  }
  for (int i = t; i < 2048; i += 256) {
    int b = i >> 6, q = i & 63;
    *(float4*)&As[b * 260 + q * 4] = *(const float4*)(pp + (size_t)b * 256 + q * 4);
  }
  __syncthreads();
  const int mf = t & 15, bg = t >> 4;
  const int b0 = bg * 2;
  float4 acc0 = make_float4(0.f, 0.f, 0.f, 0.f), acc1 = acc0;
  const float* a0 = &As[b0 * 260];
  const float* a1 = &As[(b0 + 1) * 260];
#pragma unroll 8
  for (int k = 0; k < 256; ++k) {
    float4 wv = *(const float4*)&Ws[k * 64 + mf * 4];
    fma4(acc0, a0[k], wv);
    fma4(acc1, a1[k], wv);
  }
  const float4 pbv = *(const float4*)(pb2 + m0 + mf * 4);
  const float4 gv = *(const float4*)(ong + mf * 4);
  const float4 bv = *(const float4*)(onb + mf * 4);
  acc0.x += pbv.x; acc0.y += pbv.y; acc0.z += pbv.z; acc0.w += pbv.w;
  acc1.x += pbv.x; acc1.y += pbv.y; acc1.z += pbv.z; acc1.w += pbv.w;

  // LN over o=64 for row b0 (16-lane group holds the full row)
  float s0 = group16_sum(acc0.x + acc0.y + acc0.z + acc0.w);
  float mean0 = s0 * (1.f / 64.f);
  float4 d0 = make_float4(acc0.x - mean0, acc0.y - mean0, acc0.z - mean0, acc0.w - mean0);
  float q0 = group16_sum(d0.x * d0.x + d0.y * d0.y + d0.z * d0.z + d0.w * d0.w);
  float rr0 = rsqrtf(q0 * (1.f / 64.f) + 1e-5f);
  float4 o0 = make_float4(d0.x * rr0 * gv.x + bv.x, d0.y * rr0 * gv.y + bv.y,
                          d0.z * rr0 * gv.z + bv.z, d0.w * rr0 * gv.w + bv.w);
  // row b0+1
  float s1 = group16_sum(acc1.x + acc1.y + acc1.z + acc1.w);
  float mean1 = s1 * (1.f / 64.f);
  float4 d1 = make_float4(acc1.x - mean1, acc1.y - mean1, acc1.z - mean1, acc1.w - mean1);
  float q1 = group16_sum(d1.x * d1.x + d1.y * d1.y + d1.z * d1.z + d1.w * d1.w);
  float rr1 = rsqrtf(q1 * (1.f / 64.f) + 1e-5f);
  float4 o1 = make_float4(d1.x * rr1 * gv.x + bv.x, d1.y * rr1 * gv.y + bv.y,
                          d1.z * rr1 * gv.z + bv.z, d1.w * rr1 * gv.w + bv.w);

  *(float4*)(outp + ((size_t)b0 * 96 + pi) * 64 + mf * 4) = o0;
  *(float4*)(outp + ((size_t)(b0 + 1) * 96 + pi) * 64 + mf * 4) = o1;
}

extern "C" void kernel_launch(void* const* d_in, const int* in_sizes, int n_in,
                              void* d_out, int out_size, void* d_ws, size_t ws_size,
                              hipStream_t stream) {
  (void)in_sizes; (void)n_in; (void)out_size; (void)ws_size;
  const float* x      = (const float*)d_in[0];
  const float* gW1    = (const float*)d_in[1];
  const float* gb1    = (const float*)d_in[2];
  const float* gln1_g = (const float*)d_in[3];
  const float* gln1_b = (const float*)d_in[4];
  const float* gW2    = (const float*)d_in[5];
  const float* gb2    = (const float*)d_in[6];
  const float* gln2_g = (const float*)d_in[7];
  const float* gln2_b = (const float*)d_in[8];
  const float* gW3    = (const float*)d_in[9];
  const float* gb3    = (const float*)d_in[10];
  const float* protos = (const float*)d_in[11];
  const float* temp   = (const float*)d_in[12];
  const float* eW1    = (const float*)d_in[13];
  const float* eb1    = (const float*)d_in[14];
  const float* eW2    = (const float*)d_in[15];
  const float* eb2    = (const float*)d_in[16];
  const float* fW1    = (const float*)d_in[17];
  const float* fb1    = (const float*)d_in[18];
  const float* fln_g  = (const float*)d_in[19];
  const float* fln_b  = (const float*)d_in[20];
  const float* fW2    = (const float*)d_in[21];
  const float* fb2    = (const float*)d_in[22];
  const float* ln_g   = (const float*)d_in[23];
  const float* ln_b   = (const float*)d_in[24];
  const float* pW1    = (const float*)d_in[25];
  const float* pb1    = (const float*)d_in[26];
  const float* pln_g  = (const float*)d_in[27];
  const float* pln_b  = (const float*)d_in[28];
  const float* pW2    = (const float*)d_in[29];
  const float* pb2    = (const float*)d_in[30];
  const float* on_g   = (const float*)d_in[31];
  const float* on_b   = (const float*)d_in[32];
  float* out = (float*)d_out;

  float* ws     = (float*)d_ws;
  // region 0 (2,097,152 floats): gemm1 partials; after pr_he reused as
  //   epart [0 .. 1,048,576) and he_all [1,048,576 .. 1,179,648).
  float* part   = ws;
  float* epart  = ws;
  float* he_all = ws + 1048576;
  float* h1     = ws + 2097152;     // 16384
  float* zp     = h1 + 16384;       // pre / gemm partials: up to 131072
  float* fused  = zp + 262144;      // 16384
  float* f1     = fused + 16384;    // 16384
  float* lastv  = f1 + 16384;       // 16384
  float* pp     = lastv + 16384;    // 8192

  // g-path head
  gemm1<<<dim3(4, 128), 256, 0, stream>>>(x, gW1, part);
  // part_red (256) || he_k (16)
  pr_he<<<272, 256, 0, stream>>>(part, zp, x, eW1, eb1, he_all);
  // LN1 (32) || expert gemm (512)
  ln_eg<<<544, 256, 0, stream>>>(zp, gb1, gln1_g, gln1_b, h1, he_all, eW2, epart);
  // g-path tail
  gemm_tile<64><<<dim3(8, 8), 256, 0, stream>>>(h1, gW2, zp, 512, 512);
  // LN2 + gate + ffuse, all per-b, one kernel
  gate_mix<<<32, 512, 0, stream>>>(zp, gb2, gln2_g, gln2_b, gW3, gb3, protos,
                                   temp, epart, eb2, fused);
  // f-path
  gemm_tile<64><<<dim3(8, 8), 256, 0, stream>>>(fused, fW1, zp, 512, 512);
  red_ln<<<32, 512, 0, stream>>>(zp, fb1, fln_g, fln_b, f1, 512, 8, 1);
  gemm_tile<64><<<dim3(8, 8), 256, 0, stream>>>(f1, fW2, zp, 512, 512);
  red_ln<<<32, 512, 0, stream>>>(zp, fb2, ln_g, ln_b, lastv, 512, 8, 0);
  gemm_tile<64><<<dim3(4, 8), 256, 0, stream>>>(lastv, pW1, zp, 256, 512);
  red_ln<<<32, 256, 0, stream>>>(zp, pb1, pln_g, pln_b, pp, 256, 8, 1);
  // final projection + LN(64) fused, direct to out
  pgemm_ln<<<96, 256, 0, stream>>>(pp, pW2, pb2, on_g, on_b, out);
}

// Round 9
// 273.068 us; speedup vs baseline: 1.0281x; 1.0281x over previous
//
#include <hip/hip_runtime.h>
#include <math.h>

// Shapes: B=32, S=512, I=64, H=512, E=8, P=96, O=64, EM=512; D = S*I = 32768.
#define DIMK 32768

__device__ __forceinline__ void fma4(float4& a, float s, const float4 w) {
  a.x += s * w.x; a.y += s * w.y; a.z += s * w.z; a.w += s * w.w;
}

__device__ __forceinline__ float fsel(const float4& v, int kk) {
  return kk == 0 ? v.x : kk == 1 ? v.y : kk == 2 ? v.z : v.w;
}

__device__ __forceinline__ float wave_sum(float v) {
  v += __shfl_xor(v, 1); v += __shfl_xor(v, 2); v += __shfl_xor(v, 4);
  v += __shfl_xor(v, 8); v += __shfl_xor(v, 16); v += __shfl_xor(v, 32);
  return v;
}

// Direct global->LDS DMA, 16 B per lane (dest = wave-uniform base + lane*16).
__device__ __forceinline__ void gld_lds16(const float* g, float* l) {
  __builtin_amdgcn_global_load_lds(
      (const __attribute__((address_space(1))) void*)g,
      (__attribute__((address_space(3))) void*)l, 16, 0, 0);
}

__device__ __forceinline__ float block_sum(float v, float* red, int n) {
  int t = threadIdx.x;
  red[t] = v;
  __syncthreads();
  for (int s = n >> 1; s > 0; s >>= 1) {
    if (t < s) red[t] += red[t + s];
    __syncthreads();
  }
  float r = red[0];
  __syncthreads();
  return r;
}

// ---------------------------------------------------------------------------
// gemm1: part[ks][b][m] = x(32 x 32768)[,k-slice ks] @ gW1[k-slice][m-tile].
// grid (4 mt, 128 ks) = 512 blocks (2/CU), block 256. A staged once (32 KB);
// W double-buffered 32k x 128m (16 KB) sub-stages, both via global_load_lds
// width=16. LDS 64 KB. [round-2 proven form, unchanged]
__global__ __launch_bounds__(256) void gemm1(const float* __restrict__ x,
                                             const float* __restrict__ gW1,
                                             float* __restrict__ part) {
  const int mt = blockIdx.x, ks = blockIdx.y;
  const int m0 = mt * 128, k0 = ks * 256;
  const int t = threadIdx.x;
  __shared__ float As[32 * 256];     // [b][k], 32 KB
  __shared__ float Ws[2][32 * 128];  // [k][m] sub-stage, 16 KB each

  const float* Wp = gW1 + (size_t)k0 * 512 + m0;

#pragma unroll
  for (int j = 0; j < 8; ++j) {
    int i = t + j * 256;
    gld_lds16(x + (size_t)(i >> 6) * DIMK + k0 + (i & 63) * 4, &As[i * 4]);
  }
#pragma unroll
  for (int j = 0; j < 4; ++j) {
    int i = t + j * 256;
    gld_lds16(Wp + (size_t)(i >> 5) * 512 + (i & 31) * 4, &Ws[0][i * 4]);
  }

  const int mf4 = (t & 31) * 4;
  const int bg = t >> 5;
  float4 acc[4];
#pragma unroll
  for (int j = 0; j < 4; ++j) acc[j] = make_float4(0.f, 0.f, 0.f, 0.f);
  const float* a0 = &As[bg * 4 * 256];

  for (int s = 0; s < 8; ++s) {
    __syncthreads();
    if (s < 7) {
      const float* Wn = Wp + (size_t)(s + 1) * 32 * 512;
#pragma unroll
      for (int j = 0; j < 4; ++j) {
        int i = t + j * 256;
        gld_lds16(Wn + (size_t)(i >> 5) * 512 + (i & 31) * 4, &Ws[(s + 1) & 1][i * 4]);
      }
    }
    const float* Wc = Ws[s & 1];
    const int sc = s * 32;
#pragma unroll
    for (int kq = 0; kq < 8; ++kq) {
      float4 av0 = *(const float4*)(a0 + sc + kq * 4);
      float4 av1 = *(const float4*)(a0 + 256 + sc + kq * 4);
      float4 av2 = *(const float4*)(a0 + 512 + sc + kq * 4);
      float4 av3 = *(const float4*)(a0 + 768 + sc + kq * 4);
#pragma unroll
      for (int kk = 0; kk < 4; ++kk) {
        float4 wv = *(const float4*)&Wc[(kq * 4 + kk) * 128 + mf4];
        fma4(acc[0], fsel(av0, kk), wv);
        fma4(acc[1], fsel(av1, kk), wv);
        fma4(acc[2], fsel(av2, kk), wv);
        fma4(acc[3], fsel(av3, kk), wv);
      }
    }
  }

  float* op = part + ((size_t)ks * 32 + bg * 4) * 512 + m0 + mf4;
#pragma unroll
  for (int j = 0; j < 4; ++j) *(float4*)(op + (size_t)j * 512) = acc[j];
}

// ---------------------------------------------------------------------------
// pr_he: grid 272, block 256. Independent work fused by grid partition:
// bid<256 -> part_red (pre[c][b][m] = sum 16 ks-slices); bid>=256 -> he_k.
__global__ __launch_bounds__(256) void pr_he(const float* __restrict__ part,
                                             float* __restrict__ pre,
                                             const float* __restrict__ x,
                                             const float* __restrict__ eW1,
                                             const float* __restrict__ eb1,
                                             float* __restrict__ he_all) {
  __shared__ float sm[18432];  // he_k: xs 2048 + Ws 16384 (72 KB)
  const int bid = blockIdx.x, t = threadIdx.x;
  if (bid < 256) {
    const int b = bid & 31, c = bid >> 5;
#pragma unroll
    for (int h = 0; h < 2; ++h) {
      int m = t + h * 256;
      float a = 0.f;
      const float* p = part + ((size_t)c * 16 * 32 + b) * 512 + m;
#pragma unroll
      for (int i = 0; i < 16; ++i) a += p[(size_t)i * 16384];
      pre[((size_t)c * 32 + b) * 512 + m] = a;
    }
  } else {
    const int idx = bid - 256;
    const int e = idx >> 1, hs = idx & 1;
    float* xs = sm;          // 32 x 64
    float* Ws = sm + 2048;   // 64 x 256
    for (int i = t; i < 512; i += 256) {
      int b = i >> 4, q = i & 15;
      *(float4*)&xs[b * 64 + q * 4] = *(const float4*)(x + (size_t)b * DIMK + 32704 + q * 4);
    }
    const float* w1 = eW1 + (size_t)e * 64 * 512 + hs * 256;
    for (int i = t; i < 64 * 64; i += 256) {
      int k = i >> 6, q = i & 63;
      *(float4*)&Ws[k * 256 + q * 4] = *(const float4*)(w1 + (size_t)k * 512 + q * 4);
    }
    __syncthreads();
    float acc[32];
#pragma unroll
    for (int b = 0; b < 32; ++b) acc[b] = 0.f;
#pragma unroll 4
    for (int k = 0; k < 64; ++k) {
      float wk = Ws[k * 256 + t];
#pragma unroll
      for (int b = 0; b < 32; ++b) acc[b] += xs[b * 64 + k] * wk;
    }
    float bb = eb1[e * 512 + hs * 256 + t];
    for (int b = 0; b < 32; ++b)
      he_all[((size_t)e * 32 + b) * 512 + hs * 256 + t] = fmaxf(acc[b] + bb, 0.f);
  }
}

// ---------------------------------------------------------------------------
// ln_eg: grid 544, block 256. bid<32 -> LN1; bid>=32 -> expert gemm KC=64
// (512 blocks: 8 mt x 8 kq x 8 e). [round-7 proven form]
__global__ __launch_bounds__(256) void ln_eg(const float* __restrict__ pre,
                                             const float* __restrict__ gb1,
                                             const float* __restrict__ g,
                                             const float* __restrict__ bt,
                                             float* __restrict__ h1,
                                             const float* __restrict__ he_all,
                                             const float* __restrict__ eW2,
                                             float* __restrict__ epart) {
  __shared__ float sm[6272];  // gemm: Ws 64*64 + As 32*68; LN: sm[0..4) = red4
  const int bid = blockIdx.x, t = threadIdx.x;
  if (bid < 32) {
    const int b = bid;
    float a0 = gb1[t], a1 = gb1[t + 256];
    for (int kq = 0; kq < 8; ++kq) {
      const float* p = pre + ((size_t)kq * 32 + b) * 512;
      a0 += p[t]; a1 += p[t + 256];
    }
    const int lane = t & 63, wid = t >> 6;
    float s = wave_sum(a0 + a1);
    if (lane == 0) sm[wid] = s;
    __syncthreads();
    float mean = (sm[0] + sm[1] + sm[2] + sm[3]) * (1.f / 512.f);
    float d0 = a0 - mean, d1 = a1 - mean;
    __syncthreads();
    float q = wave_sum(d0 * d0 + d1 * d1);
    if (lane == 0) sm[wid] = q;
    __syncthreads();
    float var = (sm[0] + sm[1] + sm[2] + sm[3]) * (1.f / 512.f);
    float rr = rsqrtf(var + 1e-5f);
    h1[b * 512 + t] = fmaxf(d0 * rr * g[t] + bt[t], 0.f);
    h1[b * 512 + t + 256] = fmaxf(d1 * rr * g[t + 256] + bt[t + 256], 0.f);
  } else {
    const int idx = bid - 32;
    const int mt = idx & 7, kq = (idx >> 3) & 7, e = idx >> 6;
    constexpr int KC = 64;
    float* Ws = sm;               // 64*64
    float* As = sm + KC * 64;     // 32*68
    const int m0 = mt * 64, k0 = kq * KC;
    const float* Wp = eW2 + (size_t)e * 512 * 512 + (size_t)k0 * 512 + m0;
    for (int i = t; i < KC * 16; i += 256) {
      int r = i >> 4, q = i & 15;
      *(float4*)&Ws[r * 64 + q * 4] = *(const float4*)(Wp + (size_t)r * 512 + q * 4);
    }
    const float* Ap = he_all + (size_t)e * 32 * 512 + k0;
    for (int i = t; i < 32 * (KC / 4); i += 256) {
      int b = i / (KC / 4), q = i % (KC / 4);
      *(float4*)&As[b * (KC + 4) + q * 4] = *(const float4*)(Ap + (size_t)b * 512 + q * 4);
    }
    __syncthreads();
    const int mf = t & 15, bg = t >> 4;
    const int b0 = bg * 2;
    float4 acc0 = make_float4(0.f, 0.f, 0.f, 0.f), acc1 = acc0;
    const float* a0 = &As[b0 * (KC + 4)];
    const float* a1 = &As[(b0 + 1) * (KC + 4)];
#pragma unroll 8
    for (int k = 0; k < KC; ++k) {
      float4 wv = *(const float4*)&Ws[k * 64 + mf * 4];
      fma4(acc0, a0[k], wv);
      fma4(acc1, a1[k], wv);
    }
    float* op = epart + ((size_t)(kq * 8 + e) * 32 + b0) * 512 + m0 + mf * 4;
    *(float4*)op = acc0;
    *(float4*)(op + 512) = acc1;
  }
}

// ---------------------------------------------------------------------------
// gemm_tile<KC>: C_part = A(32 x K) @ W(K x M), one (64 m x KC k) tile/block.
// grid (M/64, K/KC), block 256. [round-2 proven form]
template <int KC>
__global__ __launch_bounds__(256) void gemm_tile(const float* __restrict__ A,
                                                 const float* __restrict__ W,
                                                 float* __restrict__ outp,
                                                 int M, int aRow) {
  const int mt = blockIdx.x, kq = blockIdx.y;
  const int m0 = mt * 64, k0 = kq * KC;
  const int t = threadIdx.x;
  __shared__ float Ws[KC * 64];
  __shared__ float As[32 * (KC + 4)];
  const float* Wp = W + (size_t)k0 * M + m0;
  for (int i = t; i < KC * 16; i += 256) {
    int r = i >> 4, q = i & 15;
    *(float4*)&Ws[r * 64 + q * 4] = *(const float4*)(Wp + (size_t)r * M + q * 4);
  }
  const float* Ap = A + k0;
  for (int i = t; i < 32 * (KC / 4); i += 256) {
    int b = i / (KC / 4), q = i % (KC / 4);
    *(float4*)&As[b * (KC + 4) + q * 4] = *(const float4*)(Ap + (size_t)b * aRow + q * 4);
  }
  __syncthreads();
  const int mf = t & 15, bg = t >> 4;
  const int b0 = bg * 2;
  float4 acc0 = make_float4(0.f, 0.f, 0.f, 0.f), acc1 = acc0;
  const float* a0 = &As[b0 * (KC + 4)];
  const float* a1 = &As[(b0 + 1) * (KC + 4)];
#pragma unroll 8
  for (int k = 0; k < KC; ++k) {
    float4 wv = *(const float4*)&Ws[k * 64 + mf * 4];
    fma4(acc0, a0[k], wv);
    fma4(acc1, a1[k], wv);
  }
  float* op = outp + ((size_t)kq * 32 + b0) * M + m0 + mf * 4;
  *(float4*)op = acc0;
  *(float4*)(op + M) = acc1;
}

// ---------------------------------------------------------------------------
// red_ln: out = [relu](LN(sum_kq zp + bias)). grid 32, block M. [round-2]
__global__ void red_ln(const float* __restrict__ zp, const float* __restrict__ bias,
                       const float* __restrict__ g, const float* __restrict__ bt,
                       float* __restrict__ outp, int M, int nq, int relu) {
  const int b = blockIdx.x, t = threadIdx.x;
  __shared__ float red[512];
  float a = bias[t];
#pragma unroll 4
  for (int kq = 0; kq < nq; ++kq) a += zp[((size_t)kq * 32 + b) * M + t];
  float fM = 1.f / (float)M;
  float mean = block_sum(a, red, M) * fM;
  float d = a - mean;
  float var = block_sum(d * d, red, M) * fM;
  float v = d * rsqrtf(var + 1e-5f) * g[t] + bt[t];
  outp[b * M + t] = relu ? fmaxf(v, 0.f) : v;
}

// ---------------------------------------------------------------------------
// gate_mix: per-b mega-stage (grid 32, block 512). Fuses LN2 (row stays in
// LDS), gate gemm (gW3 re-read 256KB x 32 = 8 MB, cheap), proto distances +
// softmax (weights stay in LDS), and ffuse. [round-8 form, kept: identical
// work/threads to the 3 kernels it replaces, minus 2 launches + 2 round-trips]
__global__ __launch_bounds__(512) void gate_mix(const float* __restrict__ zp,
                                                const float* __restrict__ gb2,
                                                const float* __restrict__ g2,
                                                const float* __restrict__ bt2,
                                                const float* __restrict__ gW3,
                                                const float* __restrict__ gb3,
                                                const float* __restrict__ protos,
                                                const float* __restrict__ temp,
                                                const float* __restrict__ epart,
                                                const float* __restrict__ eb2,
                                                float* __restrict__ fused) {
  const int b = blockIdx.x, t = threadIdx.x;
  __shared__ float red[512];
  __shared__ float Arow[512];
  __shared__ float pacc[16 * 128];
  __shared__ float emb[128];
  __shared__ float d2s[8];
  __shared__ float wl[8];

  // --- LN2 ---
  float a = gb2[t];
#pragma unroll
  for (int kq = 0; kq < 8; ++kq) a += zp[((size_t)kq * 32 + b) * 512 + t];
  float mean = block_sum(a, red, 512) * (1.f / 512.f);
  float d = a - mean;
  float var = block_sum(d * d, red, 512) * (1.f / 512.f);
  Arow[t] = fmaxf(d * rsqrtf(var + 1e-5f) * g2[t] + bt2[t], 0.f);
  __syncthreads();

  // --- gate gemm: 16 kg x 32 k ---
  const int m4 = (t & 31) * 4, kg = t >> 5;
  const float* Wp = gW3 + (size_t)kg * 32 * 128 + m4;
  float4 acc = make_float4(0.f, 0.f, 0.f, 0.f);
  const float* ar = &Arow[kg * 32];
#pragma unroll 8
  for (int k = 0; k < 32; ++k) {
    float4 wv = *(const float4*)(Wp + (size_t)k * 128);
    fma4(acc, ar[k], wv);
  }
  *(float4*)&pacc[kg * 128 + m4] = acc;
  __syncthreads();
  if (t < 128) {
    float e = gb3[t];
#pragma unroll
    for (int k2 = 0; k2 < 16; ++k2) e += pacc[k2 * 128 + t];
    emb[t] = e;
  }
  __syncthreads();

  // --- distances (8 waves, one expert each) + softmax ---
  const int lane = t & 63, wid = t >> 6;
  float dd0 = emb[lane] - protos[wid * 128 + lane];
  float dd1 = emb[lane + 64] - protos[wid * 128 + 64 + lane];
  float q = wave_sum(dd0 * dd0 + dd1 * dd1);
  if (lane == 0) d2s[wid] = q;
  __syncthreads();
  if (t == 0) {
    float tt = fminf(fmaxf(temp[0], 0.1f), 5.0f);
    float lg[8], mx = -1e30f;
#pragma unroll
    for (int e = 0; e < 8; ++e) {
      float dist = sqrtf(fmaxf(d2s[e], 1e-12f));
      lg[e] = -dist / tt;
      mx = fmaxf(mx, lg[e]);
    }
    float se = 0.f;
#pragma unroll
    for (int e = 0; e < 8; ++e) { lg[e] = expf(lg[e] - mx); se += lg[e]; }
#pragma unroll
    for (int e = 0; e < 8; ++e) wl[e] = lg[e] / se;
  }
  __syncthreads();

  // --- ffuse (1 m per thread) ---
  float fa = 0.f;
#pragma unroll
  for (int e = 0; e < 8; ++e) {
    float s = eb2[e * 512 + t];
#pragma unroll
    for (int kq = 0; kq < 8; ++kq)
      s += epart[(((size_t)kq * 8 + e) * 32 + b) * 512 + t];
    fa += wl[e] * s;
  }
  fused[b * 512 + t] = fa;
}

// ---------------------------------------------------------------------------
// fin_red: out[b][pi][o] = LN_o(sum_kq fpart + pb2), kq=4. block 256 = 4 rows
// of 64 lanes; grid 768. [round-7 proven form, restored]
__global__ __launch_bounds__(256) void fin_red(const float* __restrict__ fpart,
                                               const float* __restrict__ pb2,
                                               const float* __restrict__ ong,
                                               const float* __restrict__ onb,
                                               float* __restrict__ outp) {
  const int t = threadIdx.x;
  const int lane = t & 63, w = t >> 6;
  const int r = blockIdx.x * 4 + w;  // 0..3071
  const int b = r / 96, pi = r % 96;
  const int m = pi * 64 + lane;
  float a = pb2[m];
#pragma unroll
  for (int kq = 0; kq < 4; ++kq) a += fpart[((size_t)kq * 32 + b) * 6144 + m];
  float s = wave_sum(a);
  float mean = s * (1.f / 64.f);
  float d = a - mean;
  float q = wave_sum(d * d);
  float rr = rsqrtf(q * (1.f / 64.f) + 1e-5f);
  outp[((size_t)b * 96 + pi) * 64 + lane] = d * rr * ong[lane] + onb[lane];
}

extern "C" void kernel_launch(void* const* d_in, const int* in_sizes, int n_in,
                              void* d_out, int out_size, void* d_ws, size_t ws_size,
                              hipStream_t stream) {
  (void)in_sizes; (void)n_in; (void)out_size; (void)ws_size;
  const float* x      = (const float*)d_in[0];
  const float* gW1    = (const float*)d_in[1];
  const float* gb1    = (const float*)d_in[2];
  const float* gln1_g = (const float*)d_in[3];
  const float* gln1_b = (const float*)d_in[4];
  const float* gW2    = (const float*)d_in[5];
  const float* gb2    = (const float*)d_in[6];
  const float* gln2_g = (const float*)d_in[7];
  const float* gln2_b = (const float*)d_in[8];
  const float* gW3    = (const float*)d_in[9];
  const float* gb3    = (const float*)d_in[10];
  const float* protos = (const float*)d_in[11];
  const float* temp   = (const float*)d_in[12];
  const float* eW1    = (const float*)d_in[13];
  const float* eb1    = (const float*)d_in[14];
  const float* eW2    = (const float*)d_in[15];
  const float* eb2    = (const float*)d_in[16];
  const float* fW1    = (const float*)d_in[17];
  const float* fb1    = (const float*)d_in[18];
  const float* fln_g  = (const float*)d_in[19];
  const float* fln_b  = (const float*)d_in[20];
  const float* fW2    = (const float*)d_in[21];
  const float* fb2    = (const float*)d_in[22];
  const float* ln_g   = (const float*)d_in[23];
  const float* ln_b   = (const float*)d_in[24];
  const float* pW1    = (const float*)d_in[25];
  const float* pb1    = (const float*)d_in[26];
  const float* pln_g  = (const float*)d_in[27];
  const float* pln_b  = (const float*)d_in[28];
  const float* pW2    = (const float*)d_in[29];
  const float* pb2    = (const float*)d_in[30];
  const float* on_g   = (const float*)d_in[31];
  const float* on_b   = (const float*)d_in[32];
  float* out = (float*)d_out;

  float* ws     = (float*)d_ws;
  // region 0 (2,097,152 floats): gemm1 partials; after pr_he reused as
  //   epart [0 .. 1,048,576) and he_all [1,048,576 .. 1,179,648);
  //   after gate_mix reused as fpart [0 .. 786,432).
  float* part   = ws;
  float* epart  = ws;
  float* he_all = ws + 1048576;
  float* fpart  = ws;
  float* h1     = ws + 2097152;     // 16384
  float* zp     = h1 + 16384;       // pre / gemm partials: up to 131072
  float* fused  = zp + 262144;      // 16384
  float* f1     = fused + 16384;    // 16384
  float* lastv  = f1 + 16384;       // 16384
  float* pp     = lastv + 16384;    // 8192

  // g-path head
  gemm1<<<dim3(4, 128), 256, 0, stream>>>(x, gW1, part);
  // part_red (256) || he_k (16)
  pr_he<<<272, 256, 0, stream>>>(part, zp, x, eW1, eb1, he_all);
  // LN1 (32) || expert gemm (512)
  ln_eg<<<544, 256, 0, stream>>>(zp, gb1, gln1_g, gln1_b, h1, he_all, eW2, epart);
  // g-path tail
  gemm_tile<64><<<dim3(8, 8), 256, 0, stream>>>(h1, gW2, zp, 512, 512);
  // LN2 + gate + ffuse, all per-b, one kernel
  gate_mix<<<32, 512, 0, stream>>>(zp, gb2, gln2_g, gln2_b, gW3, gb3, protos,
                                   temp, epart, eb2, fused);
  // f-path
  gemm_tile<64><<<dim3(8, 8), 256, 0, stream>>>(fused, fW1, zp, 512, 512);
  red_ln<<<32, 512, 0, stream>>>(zp, fb1, fln_g, fln_b, f1, 512, 8, 1);
  gemm_tile<64><<<dim3(8, 8), 256, 0, stream>>>(f1, fW2, zp, 512, 512);
  red_ln<<<32, 512, 0, stream>>>(zp, fb2, ln_g, ln_b, lastv, 512, 8, 0);
  gemm_tile<64><<<dim3(4, 8), 256, 0, stream>>>(lastv, pW1, zp, 256, 512);
  red_ln<<<32, 256, 0, stream>>>(zp, pb1, pln_g, pln_b, pp, 256, 8, 1);
  // final projection + LN(64) [round-7 parallel tail restored]
  gemm_tile<64><<<dim3(96, 4), 256, 0, stream>>>(pp, pW2, fpart, 6144, 256);
  fin_red<<<768, 256, 0, stream>>>(fpart, pb2, on_g, on_b, out);
}

// Round 10
// 256.406 us; speedup vs baseline: 1.0949x; 1.0650x over previous
//
#include <hip/hip_runtime.h>
#include <math.h>

// Shapes: B=32, S=512, I=64, H=512, E=8, P=96, O=64, EM=512; D = S*I = 32768.
#define DIMK 32768

__device__ __forceinline__ void fma4(float4& a, float s, const float4 w) {
  a.x += s * w.x; a.y += s * w.y; a.z += s * w.z; a.w += s * w.w;
}

__device__ __forceinline__ float fsel(const float4& v, int kk) {
  return kk == 0 ? v.x : kk == 1 ? v.y : kk == 2 ? v.z : v.w;
}

__device__ __forceinline__ float wave_sum(float v) {
  v += __shfl_xor(v, 1); v += __shfl_xor(v, 2); v += __shfl_xor(v, 4);
  v += __shfl_xor(v, 8); v += __shfl_xor(v, 16); v += __shfl_xor(v, 32);
  return v;
}

// Direct global->LDS DMA, 16 B per lane (dest = wave-uniform base + lane*16).
__device__ __forceinline__ void gld_lds16(const float* g, float* l) {
  __builtin_amdgcn_global_load_lds(
      (const __attribute__((address_space(1))) void*)g,
      (__attribute__((address_space(3))) void*)l, 16, 0, 0);
}

__device__ __forceinline__ float block_sum(float v, float* red, int n) {
  int t = threadIdx.x;
  red[t] = v;
  __syncthreads();
  for (int s = n >> 1; s > 0; s >>= 1) {
    if (t < s) red[t] += red[t + s];
    __syncthreads();
  }
  float r = red[0];
  __syncthreads();
  return r;
}

// ---------------------------------------------------------------------------
// gemm1: part[ks][b][m] = x(32 x 32768)[,k-slice ks] @ gW1[k-slice][m-tile].
// grid (4 mt, 128 ks) = 512 blocks (2/CU), block 256. A staged once (32 KB);
// W double-buffered 32k x 128m (16 KB) sub-stages, both via global_load_lds
// width=16. LDS 64 KB. [round-2 proven form, unchanged]
__global__ __launch_bounds__(256) void gemm1(const float* __restrict__ x,
                                             const float* __restrict__ gW1,
                                             float* __restrict__ part) {
  const int mt = blockIdx.x, ks = blockIdx.y;
  const int m0 = mt * 128, k0 = ks * 256;
  const int t = threadIdx.x;
  __shared__ float As[32 * 256];     // [b][k], 32 KB
  __shared__ float Ws[2][32 * 128];  // [k][m] sub-stage, 16 KB each

  const float* Wp = gW1 + (size_t)k0 * 512 + m0;

#pragma unroll
  for (int j = 0; j < 8; ++j) {
    int i = t + j * 256;
    gld_lds16(x + (size_t)(i >> 6) * DIMK + k0 + (i & 63) * 4, &As[i * 4]);
  }
#pragma unroll
  for (int j = 0; j < 4; ++j) {
    int i = t + j * 256;
    gld_lds16(Wp + (size_t)(i >> 5) * 512 + (i & 31) * 4, &Ws[0][i * 4]);
  }

  const int mf4 = (t & 31) * 4;
  const int bg = t >> 5;
  float4 acc[4];
#pragma unroll
  for (int j = 0; j < 4; ++j) acc[j] = make_float4(0.f, 0.f, 0.f, 0.f);
  const float* a0 = &As[bg * 4 * 256];

  for (int s = 0; s < 8; ++s) {
    __syncthreads();
    if (s < 7) {
      const float* Wn = Wp + (size_t)(s + 1) * 32 * 512;
#pragma unroll
      for (int j = 0; j < 4; ++j) {
        int i = t + j * 256;
        gld_lds16(Wn + (size_t)(i >> 5) * 512 + (i & 31) * 4, &Ws[(s + 1) & 1][i * 4]);
      }
    }
    const float* Wc = Ws[s & 1];
    const int sc = s * 32;
#pragma unroll
    for (int kq = 0; kq < 8; ++kq) {
      float4 av0 = *(const float4*)(a0 + sc + kq * 4);
      float4 av1 = *(const float4*)(a0 + 256 + sc + kq * 4);
      float4 av2 = *(const float4*)(a0 + 512 + sc + kq * 4);
      float4 av3 = *(const float4*)(a0 + 768 + sc + kq * 4);
#pragma unroll
      for (int kk = 0; kk < 4; ++kk) {
        float4 wv = *(const float4*)&Wc[(kq * 4 + kk) * 128 + mf4];
        fma4(acc[0], fsel(av0, kk), wv);
        fma4(acc[1], fsel(av1, kk), wv);
        fma4(acc[2], fsel(av2, kk), wv);
        fma4(acc[3], fsel(av3, kk), wv);
      }
    }
  }

  float* op = part + ((size_t)ks * 32 + bg * 4) * 512 + m0 + mf4;
#pragma unroll
  for (int j = 0; j < 4; ++j) *(float4*)(op + (size_t)j * 512) = acc[j];
}

// ---------------------------------------------------------------------------
// pr_he: grid 272, block 256. Independent work fused by grid partition:
// bid<256 -> part_red (pre[c][b][m] = sum 16 ks-slices); bid>=256 -> he_k.
__global__ __launch_bounds__(256) void pr_he(const float* __restrict__ part,
                                             float* __restrict__ pre,
                                             const float* __restrict__ x,
                                             const float* __restrict__ eW1,
                                             const float* __restrict__ eb1,
                                             float* __restrict__ he_all) {
  __shared__ float sm[18432];  // he_k: xs 2048 + Ws 16384 (72 KB)
  const int bid = blockIdx.x, t = threadIdx.x;
  if (bid < 256) {
    const int b = bid & 31, c = bid >> 5;
#pragma unroll
    for (int h = 0; h < 2; ++h) {
      int m = t + h * 256;
      float a = 0.f;
      const float* p = part + ((size_t)c * 16 * 32 + b) * 512 + m;
#pragma unroll
      for (int i = 0; i < 16; ++i) a += p[(size_t)i * 16384];
      pre[((size_t)c * 32 + b) * 512 + m] = a;
    }
  } else {
    const int idx = bid - 256;
    const int e = idx >> 1, hs = idx & 1;
    float* xs = sm;          // 32 x 64
    float* Ws = sm + 2048;   // 64 x 256
    for (int i = t; i < 512; i += 256) {
      int b = i >> 4, q = i & 15;
      *(float4*)&xs[b * 64 + q * 4] = *(const float4*)(x + (size_t)b * DIMK + 32704 + q * 4);
    }
    const float* w1 = eW1 + (size_t)e * 64 * 512 + hs * 256;
    for (int i = t; i < 64 * 64; i += 256) {
      int k = i >> 6, q = i & 63;
      *(float4*)&Ws[k * 256 + q * 4] = *(const float4*)(w1 + (size_t)k * 512 + q * 4);
    }
    __syncthreads();
    float acc[32];
#pragma unroll
    for (int b = 0; b < 32; ++b) acc[b] = 0.f;
#pragma unroll 4
    for (int k = 0; k < 64; ++k) {
      float wk = Ws[k * 256 + t];
#pragma unroll
      for (int b = 0; b < 32; ++b) acc[b] += xs[b * 64 + k] * wk;
    }
    float bb = eb1[e * 512 + hs * 256 + t];
    for (int b = 0; b < 32; ++b)
      he_all[((size_t)e * 32 + b) * 512 + hs * 256 + t] = fmaxf(acc[b] + bb, 0.f);
  }
}

// ---------------------------------------------------------------------------
// ln_eg: grid 544, block 256. bid<32 -> LN1; bid>=32 -> expert gemm KC=64
// (512 blocks: 8 mt x 8 kq x 8 e). [round-7 proven form]
__global__ __launch_bounds__(256) void ln_eg(const float* __restrict__ pre,
                                             const float* __restrict__ gb1,
                                             const float* __restrict__ g,
                                             const float* __restrict__ bt,
                                             float* __restrict__ h1,
                                             const float* __restrict__ he_all,
                                             const float* __restrict__ eW2,
                                             float* __restrict__ epart) {
  __shared__ float sm[6272];  // gemm: Ws 64*64 + As 32*68; LN: sm[0..4) = red4
  const int bid = blockIdx.x, t = threadIdx.x;
  if (bid < 32) {
    const int b = bid;
    float a0 = gb1[t], a1 = gb1[t + 256];
    for (int kq = 0; kq < 8; ++kq) {
      const float* p = pre + ((size_t)kq * 32 + b) * 512;
      a0 += p[t]; a1 += p[t + 256];
    }
    const int lane = t & 63, wid = t >> 6;
    float s = wave_sum(a0 + a1);
    if (lane == 0) sm[wid] = s;
    __syncthreads();
    float mean = (sm[0] + sm[1] + sm[2] + sm[3]) * (1.f / 512.f);
    float d0 = a0 - mean, d1 = a1 - mean;
    __syncthreads();
    float q = wave_sum(d0 * d0 + d1 * d1);
    if (lane == 0) sm[wid] = q;
    __syncthreads();
    float var = (sm[0] + sm[1] + sm[2] + sm[3]) * (1.f / 512.f);
    float rr = rsqrtf(var + 1e-5f);
    h1[b * 512 + t] = fmaxf(d0 * rr * g[t] + bt[t], 0.f);
    h1[b * 512 + t + 256] = fmaxf(d1 * rr * g[t + 256] + bt[t + 256], 0.f);
  } else {
    const int idx = bid - 32;
    const int mt = idx & 7, kq = (idx >> 3) & 7, e = idx >> 6;
    constexpr int KC = 64;
    float* Ws = sm;               // 64*64
    float* As = sm + KC * 64;     // 32*68
    const int m0 = mt * 64, k0 = kq * KC;
    const float* Wp = eW2 + (size_t)e * 512 * 512 + (size_t)k0 * 512 + m0;
    for (int i = t; i < KC * 16; i += 256) {
      int r = i >> 4, q = i & 15;
      *(float4*)&Ws[r * 64 + q * 4] = *(const float4*)(Wp + (size_t)r * 512 + q * 4);
    }
    const float* Ap = he_all + (size_t)e * 32 * 512 + k0;
    for (int i = t; i < 32 * (KC / 4); i += 256) {
      int b = i / (KC / 4), q = i % (KC / 4);
      *(float4*)&As[b * (KC + 4) + q * 4] = *(const float4*)(Ap + (size_t)b * 512 + q * 4);
    }
    __syncthreads();
    const int mf = t & 15, bg = t >> 4;
    const int b0 = bg * 2;
    float4 acc0 = make_float4(0.f, 0.f, 0.f, 0.f), acc1 = acc0;
    const float* a0 = &As[b0 * (KC + 4)];
    const float* a1 = &As[(b0 + 1) * (KC + 4)];
#pragma unroll 8
    for (int k = 0; k < KC; ++k) {
      float4 wv = *(const float4*)&Ws[k * 64 + mf * 4];
      fma4(acc0, a0[k], wv);
      fma4(acc1, a1[k], wv);
    }
    float* op = epart + ((size_t)(kq * 8 + e) * 32 + b0) * 512 + m0 + mf * 4;
    *(float4*)op = acc0;
    *(float4*)(op + 512) = acc1;
  }
}

// ---------------------------------------------------------------------------
// gemm_tile<KC>: C_part = A(32 x K) @ W(K x M), one (64 m x KC k) tile/block.
// grid (M/64, K/KC), block 256. [round-2 proven form]
template <int KC>
__global__ __launch_bounds__(256) void gemm_tile(const float* __restrict__ A,
                                                 const float* __restrict__ W,
                                                 float* __restrict__ outp,
                                                 int M, int aRow) {
  const int mt = blockIdx.x, kq = blockIdx.y;
  const int m0 = mt * 64, k0 = kq * KC;
  const int t = threadIdx.x;
  __shared__ float Ws[KC * 64];
  __shared__ float As[32 * (KC + 4)];
  const float* Wp = W + (size_t)k0 * M + m0;
  for (int i = t; i < KC * 16; i += 256) {
    int r = i >> 4, q = i & 15;
    *(float4*)&Ws[r * 64 + q * 4] = *(const float4*)(Wp + (size_t)r * M + q * 4);
  }
  const float* Ap = A + k0;
  for (int i = t; i < 32 * (KC / 4); i += 256) {
    int b = i / (KC / 4), q = i % (KC / 4);
    *(float4*)&As[b * (KC + 4) + q * 4] = *(const float4*)(Ap + (size_t)b * aRow + q * 4);
  }
  __syncthreads();
  const int mf = t & 15, bg = t >> 4;
  const int b0 = bg * 2;
  float4 acc0 = make_float4(0.f, 0.f, 0.f, 0.f), acc1 = acc0;
  const float* a0 = &As[b0 * (KC + 4)];
  const float* a1 = &As[(b0 + 1) * (KC + 4)];
#pragma unroll 8
  for (int k = 0; k < KC; ++k) {
    float4 wv = *(const float4*)&Ws[k * 64 + mf * 4];
    fma4(acc0, a0[k], wv);
    fma4(acc1, a1[k], wv);
  }
  float* op = outp + ((size_t)kq * 32 + b0) * M + m0 + mf * 4;
  *(float4*)op = acc0;
  *(float4*)(op + M) = acc1;
}

// ---------------------------------------------------------------------------
// red_ln: out = [relu](LN(sum_kq zp + bias)). grid 32, block M. [round-2]
__global__ void red_ln(const float* __restrict__ zp, const float* __restrict__ bias,
                       const float* __restrict__ g, const float* __restrict__ bt,
                       float* __restrict__ outp, int M, int nq, int relu) {
  const int b = blockIdx.x, t = threadIdx.x;
  __shared__ float red[512];
  float a = bias[t];
#pragma unroll 4
  for (int kq = 0; kq < nq; ++kq) a += zp[((size_t)kq * 32 + b) * M + t];
  float fM = 1.f / (float)M;
  float mean = block_sum(a, red, M) * fM;
  float d = a - mean;
  float var = block_sum(d * d, red, M) * fM;
  float v = d * rsqrtf(var + 1e-5f) * g[t] + bt[t];
  outp[b * M + t] = relu ? fmaxf(v, 0.f) : v;
}

// ---------------------------------------------------------------------------
// ln2_gate: grid 32, block 512. Fuses ONLY the small-traffic per-b phases:
// LN2 (zp 512 KB; h2 row stays in LDS) + gate gemm (gW3 8 MB total, L2-warm)
// + proto distances + softmax -> wgt. The 4 MB ffuse read stays in its own
// 128-block kernel (round-9 lesson: multi-MB reads need chip parallelism).
__global__ __launch_bounds__(512) void ln2_gate(const float* __restrict__ zp,
                                                const float* __restrict__ gb2,
                                                const float* __restrict__ g2,
                                                const float* __restrict__ bt2,
                                                const float* __restrict__ gW3,
                                                const float* __restrict__ gb3,
                                                const float* __restrict__ protos,
                                                const float* __restrict__ temp,
                                                float* __restrict__ wgt) {
  const int b = blockIdx.x, t = threadIdx.x;
  __shared__ float red[512];
  __shared__ float Arow[512];
  __shared__ float pacc[16 * 128];
  __shared__ float emb[128];
  __shared__ float d2s[8];

  // --- LN2 ---
  float a = gb2[t];
#pragma unroll
  for (int kq = 0; kq < 8; ++kq) a += zp[((size_t)kq * 32 + b) * 512 + t];
  float mean = block_sum(a, red, 512) * (1.f / 512.f);
  float d = a - mean;
  float var = block_sum(d * d, red, 512) * (1.f / 512.f);
  Arow[t] = fmaxf(d * rsqrtf(var + 1e-5f) * g2[t] + bt2[t], 0.f);
  __syncthreads();

  // --- gate gemm: 16 kg x 32 k ---
  const int m4 = (t & 31) * 4, kg = t >> 5;
  const float* Wp = gW3 + (size_t)kg * 32 * 128 + m4;
  float4 acc = make_float4(0.f, 0.f, 0.f, 0.f);
  const float* ar = &Arow[kg * 32];
#pragma unroll 8
  for (int k = 0; k < 32; ++k) {
    float4 wv = *(const float4*)(Wp + (size_t)k * 128);
    fma4(acc, ar[k], wv);
  }
  *(float4*)&pacc[kg * 128 + m4] = acc;
  __syncthreads();
  if (t < 128) {
    float e = gb3[t];
#pragma unroll
    for (int k2 = 0; k2 < 16; ++k2) e += pacc[k2 * 128 + t];
    emb[t] = e;
  }
  __syncthreads();

  // --- distances (8 waves, one expert each) + softmax ---
  const int lane = t & 63, wid = t >> 6;
  float dd0 = emb[lane] - protos[wid * 128 + lane];
  float dd1 = emb[lane + 64] - protos[wid * 128 + 64 + lane];
  float q = wave_sum(dd0 * dd0 + dd1 * dd1);
  if (lane == 0) d2s[wid] = q;
  __syncthreads();
  if (t == 0) {
    float tt = fminf(fmaxf(temp[0], 0.1f), 5.0f);
    float lg[8], mx = -1e30f;
#pragma unroll
    for (int e = 0; e < 8; ++e) {
      float dist = sqrtf(fmaxf(d2s[e], 1e-12f));
      lg[e] = -dist / tt;
      mx = fmaxf(mx, lg[e]);
    }
    float se = 0.f;
#pragma unroll
    for (int e = 0; e < 8; ++e) { lg[e] = expf(lg[e] - mx); se += lg[e]; }
#pragma unroll
    for (int e = 0; e < 8; ++e) wgt[b * 8 + e] = lg[e] / se;
  }
}

// ---------------------------------------------------------------------------
// ffuse: fused[b][m] = sum_e w[b,e]*(sum_kq epart + eb2[e]), kq=8.
// grid (32 b, 4 m-chunks), block 128 -- chip-parallel 4 MB read. [round-7]
__global__ __launch_bounds__(128) void ffuse(const float* __restrict__ epart,
                                             const float* __restrict__ eb2,
                                             const float* __restrict__ wgt,
                                             float* __restrict__ fused) {
  const int b = blockIdx.x, t = blockIdx.y * 128 + threadIdx.x;
  __shared__ float wl[8];
  if (threadIdx.x < 8) wl[threadIdx.x] = wgt[b * 8 + threadIdx.x];
  __syncthreads();
  float a = 0.f;
#pragma unroll
  for (int e = 0; e < 8; ++e) {
    float s = eb2[e * 512 + t];
#pragma unroll
    for (int kq = 0; kq < 8; ++kq)
      s += epart[(((size_t)kq * 8 + e) * 32 + b) * 512 + t];
    a += wl[e] * s;
  }
  fused[b * 512 + t] = a;
}

// ---------------------------------------------------------------------------
// fin_red: out[b][pi][o] = LN_o(sum_kq fpart + pb2), kq=4. block 256 = 4 rows
// of 64 lanes; grid 768. [round-7 proven form]
__global__ __launch_bounds__(256) void fin_red(const float* __restrict__ fpart,
                                               const float* __restrict__ pb2,
                                               const float* __restrict__ ong,
                                               const float* __restrict__ onb,
                                               float* __restrict__ outp) {
  const int t = threadIdx.x;
  const int lane = t & 63, w = t >> 6;
  const int r = blockIdx.x * 4 + w;  // 0..3071
  const int b = r / 96, pi = r % 96;
  const int m = pi * 64 + lane;
  float a = pb2[m];
#pragma unroll
  for (int kq = 0; kq < 4; ++kq) a += fpart[((size_t)kq * 32 + b) * 6144 + m];
  float s = wave_sum(a);
  float mean = s * (1.f / 64.f);
  float d = a - mean;
  float q = wave_sum(d * d);
  float rr = rsqrtf(q * (1.f / 64.f) + 1e-5f);
  outp[((size_t)b * 96 + pi) * 64 + lane] = d * rr * ong[lane] + onb[lane];
}

extern "C" void kernel_launch(void* const* d_in, const int* in_sizes, int n_in,
                              void* d_out, int out_size, void* d_ws, size_t ws_size,
                              hipStream_t stream) {
  (void)in_sizes; (void)n_in; (void)out_size; (void)ws_size;
  const float* x      = (const float*)d_in[0];
  const float* gW1    = (const float*)d_in[1];
  const float* gb1    = (const float*)d_in[2];
  const float* gln1_g = (const float*)d_in[3];
  const float* gln1_b = (const float*)d_in[4];
  const float* gW2    = (const float*)d_in[5];
  const float* gb2    = (const float*)d_in[6];
  const float* gln2_g = (const float*)d_in[7];
  const float* gln2_b = (const float*)d_in[8];
  const float* gW3    = (const float*)d_in[9];
  const float* gb3    = (const float*)d_in[10];
  const float* protos = (const float*)d_in[11];
  const float* temp   = (const float*)d_in[12];
  const float* eW1    = (const float*)d_in[13];
  const float* eb1    = (const float*)d_in[14];
  const float* eW2    = (const float*)d_in[15];
  const float* eb2    = (const float*)d_in[16];
  const float* fW1    = (const float*)d_in[17];
  const float* fb1    = (const float*)d_in[18];
  const float* fln_g  = (const float*)d_in[19];
  const float* fln_b  = (const float*)d_in[20];
  const float* fW2    = (const float*)d_in[21];
  const float* fb2    = (const float*)d_in[22];
  const float* ln_g   = (const float*)d_in[23];
  const float* ln_b   = (const float*)d_in[24];
  const float* pW1    = (const float*)d_in[25];
  const float* pb1    = (const float*)d_in[26];
  const float* pln_g  = (const float*)d_in[27];
  const float* pln_b  = (const float*)d_in[28];
  const float* pW2    = (const float*)d_in[29];
  const float* pb2    = (const float*)d_in[30];
  const float* on_g   = (const float*)d_in[31];
  const float* on_b   = (const float*)d_in[32];
  float* out = (float*)d_out;

  float* ws     = (float*)d_ws;
  // region 0 (2,097,152 floats): gemm1 partials; after pr_he reused as
  //   epart [0 .. 1,048,576) and he_all [1,048,576 .. 1,179,648);
  //   after ffuse reused as fpart [0 .. 786,432).
  float* part   = ws;
  float* epart  = ws;
  float* he_all = ws + 1048576;
  float* fpart  = ws;
  float* h1     = ws + 2097152;     // 16384
  float* zp     = h1 + 16384;       // pre / gemm partials: up to 131072
  float* wgt    = zp + 262144;      // 256
  float* fused  = wgt + 256;        // 16384
  float* f1     = fused + 16384;    // 16384
  float* lastv  = f1 + 16384;       // 16384
  float* pp     = lastv + 16384;    // 8192

  // g-path head
  gemm1<<<dim3(4, 128), 256, 0, stream>>>(x, gW1, part);
  // part_red (256) || he_k (16)
  pr_he<<<272, 256, 0, stream>>>(part, zp, x, eW1, eb1, he_all);
  // LN1 (32) || expert gemm (512)
  ln_eg<<<544, 256, 0, stream>>>(zp, gb1, gln1_g, gln1_b, h1, he_all, eW2, epart);
  // g-path tail
  gemm_tile<64><<<dim3(8, 8), 256, 0, stream>>>(h1, gW2, zp, 512, 512);
  // LN2 + gate (small-traffic per-b phases only)
  ln2_gate<<<32, 512, 0, stream>>>(zp, gb2, gln2_g, gln2_b, gW3, gb3, protos,
                                   temp, wgt);
  // expert mix at chip parallelism
  ffuse<<<dim3(32, 4), 128, 0, stream>>>(epart, eb2, wgt, fused);
  // f-path
  gemm_tile<64><<<dim3(8, 8), 256, 0, stream>>>(fused, fW1, zp, 512, 512);
  red_ln<<<32, 512, 0, stream>>>(zp, fb1, fln_g, fln_b, f1, 512, 8, 1);
  gemm_tile<64><<<dim3(8, 8), 256, 0, stream>>>(f1, fW2, zp, 512, 512);
  red_ln<<<32, 512, 0, stream>>>(zp, fb2, ln_g, ln_b, lastv, 512, 8, 0);
  gemm_tile<64><<<dim3(4, 8), 256, 0, stream>>>(lastv, pW1, zp, 256, 512);
  red_ln<<<32, 256, 0, stream>>>(zp, pb1, pln_g, pln_b, pp, 256, 8, 1);
  // final projection + LN(64)
  gemm_tile<64><<<dim3(96, 4), 256, 0, stream>>>(pp, pW2, fpart, 6144, 256);
  fin_red<<<768, 256, 0, stream>>>(fpart, pb2, on_g, on_b, out);
}